// Round 5
// baseline (7825.038 us; speedup 1.0000x reference)
//
#include <hip/hip_runtime.h>
#include <hip/hip_bf16.h>
#include <stdint.h>

typedef unsigned int uint;
typedef unsigned long long u64;

#define T_STEPS 128
#define BQ 16
#define HID 512
#define NSLOT 1024
#define MD 64
#define VOCAB 32000
#define BETA 1.000001f
#define EPSN 1e-8f

#define NB_PROJ 128
#define NB_BATCH 16
#define NB_REC (NB_PROJ + NB_BATCH)      // 144
#define GEMM_MT 16
#define GEMM_NT 500
#define NB_GEMM (GEMM_MT*GEMM_NT)        // 8000

// flag lines (128B apart): [0..15] hgen, [16..31] tgen(gemm), [32..159] kgen, [160..287] ggen
#define F_H(b) (((b))*32)
#define F_T(b) ((16+(b))*32)
#define F_K(w) ((32+(w))*32)
#define F_G(w) ((160+(w))*32)
#define NFLAGS 288

// agent-coherent (bypass L1/L2) ops; batched waitcnt (+sched_barrier, rule #18)
#define AL4(dst, p) asm volatile("global_load_dwordx4 %0, %1, off sc0 sc1" : "=v"(dst) : "v"(p))
#define AWAIT() do { asm volatile("s_waitcnt vmcnt(0)" ::: "memory"); __builtin_amdgcn_sched_barrier(0); } while(0)

__device__ __forceinline__ float sigm(float x){ return 1.f/(1.f+expf(-x)); }
__device__ __forceinline__ void astoref(float* p, float v){
  __hip_atomic_store(p, v, __ATOMIC_RELAXED, __HIP_MEMORY_SCOPE_AGENT);
}
__device__ __forceinline__ void astoreu32(uint* p, uint v){
  __hip_atomic_store(p, v, __ATOMIC_RELAXED, __HIP_MEMORY_SCOPE_AGENT);
}
__device__ __forceinline__ uint aloadu32(const uint* p){
  return __hip_atomic_load((uint*)p, __ATOMIC_RELAXED, __HIP_MEMORY_SCOPE_AGENT);
}
__device__ __forceinline__ void poll1(const uint* p, uint gen){
  while (aloadu32(p) < gen) __builtin_amdgcn_s_sleep(1);
}
__device__ __forceinline__ void poll64(const uint* p, uint gen){
  while (aloadu32(p) < gen) __builtin_amdgcn_s_sleep(64);
}
__device__ __forceinline__ void arrive1(uint* line, uint gen){
  asm volatile("s_waitcnt vmcnt(0)" ::: "memory");
  __syncthreads();
  if (threadIdx.x == 0) astoreu32(line, gen);
}

// pack (score, slot): u64 max == (max value, min slot on ties) — matches lax.top_k
__device__ __forceinline__ u64 packsc(float v, int slot){
  uint u = __float_as_uint(v);
  u = (u & 0x80000000u) ? ~u : (u | 0x80000000u);
  return ((u64)u << 10) | (u64)(1023 - slot);
}
__device__ __forceinline__ float unpackval(u64 p){
  uint u = (uint)(p >> 10);
  uint bits = (u & 0x80000000u) ? (u & 0x7fffffffu) : ~u;
  return __uint_as_float(bits);
}
__device__ __forceinline__ int unpackslot(u64 p){ return 1023 - (int)(p & 1023u); }

// ---------------- pre-kernels ----------------
__global__ __launch_bounds__(256) void prep_emb(const float* __restrict__ E,
                                                const int* __restrict__ seq,
                                                float* __restrict__ EMB){
  int m = blockIdx.x, t = m >> 4, b = m & 15;
  int x = seq[b*T_STEPS + t];
  EMB[(size_t)m*256 + threadIdx.x] = E[(size_t)x*256 + threadIdx.x];
}

// G_emb[m][p] packed p=u*4+g, r=g*512+u
__global__ __launch_bounds__(256) void gemm_emb(const float* __restrict__ A,
                                                const float* __restrict__ W_ih,
                                                const float* __restrict__ b_ih,
                                                const float* __restrict__ b_hh,
                                                float* __restrict__ C){
  __shared__ __align__(16) float As[16*68];
  __shared__ __align__(16) float Bs[16*68];
  int mt = blockIdx.x & 31, nt = blockIdx.x >> 5;
  int m0 = mt*64, n0 = nt*64;
  int tx = threadIdx.x & 15, ty = threadIdx.x >> 4;
  float acc[4][4] = {};
  for (int k0 = 0; k0 < 256; k0 += 16){
    int mm = threadIdx.x >> 2, kq = (threadIdx.x & 3)*4;
    float4 a = *(const float4*)(A + (size_t)(m0+mm)*256 + k0 + kq);
    As[(kq+0)*68+mm]=a.x; As[(kq+1)*68+mm]=a.y; As[(kq+2)*68+mm]=a.z; As[(kq+3)*68+mm]=a.w;
    int pp = n0 + mm;
    int r = (pp & 3)*512 + (pp >> 2);
    float4 bv = *(const float4*)(W_ih + (size_t)r*320 + k0 + kq);
    Bs[(kq+0)*68+mm]=bv.x; Bs[(kq+1)*68+mm]=bv.y; Bs[(kq+2)*68+mm]=bv.z; Bs[(kq+3)*68+mm]=bv.w;
    __syncthreads();
    #pragma unroll
    for (int kk = 0; kk < 16; ++kk){
      float4 av = *(const float4*)(As + kk*68 + ty*4);
      float4 bb = *(const float4*)(Bs + kk*68 + tx*4);
      float aa[4] = {av.x,av.y,av.z,av.w};
      float bv2[4] = {bb.x,bb.y,bb.z,bb.w};
      #pragma unroll
      for (int i = 0; i < 4; ++i)
        #pragma unroll
        for (int j = 0; j < 4; ++j)
          acc[i][j] = fmaf(aa[i], bv2[j], acc[i][j]);
    }
    __syncthreads();
  }
  #pragma unroll
  for (int i = 0; i < 4; ++i){
    int m = m0 + ty*4 + i;
    #pragma unroll
    for (int j = 0; j < 4; ++j){
      int pp = n0 + tx*4 + j;
      int r = (pp & 3)*512 + (pp >> 2);
      C[(size_t)m*2048 + pp] = acc[i][j] + b_ih[r] + b_hh[r];
    }
  }
}

// WT[k][p] = W_ih[r(p)][256+k]  (packed-p rv-weight transpose)
__global__ __launch_bounds__(256) void make_wrvT(const float* __restrict__ W_ih,
                                                 float* __restrict__ WT){
  int idx = blockIdx.x*256 + threadIdx.x;   // 0..131071
  int k = idx >> 11, p = idx & 2047;
  int r = (p & 3)*512 + (p >> 2);
  WT[idx] = W_ih[(size_t)r*320 + 256 + k];
}

// ---------------- the fused mega-kernel ----------------
// blocks [0,128): proj/gate WGs; [128,144): batch WGs; [144,8144): gemm tiles
__global__ __launch_bounds__(256, 2) void mega_kernel(
    const float* __restrict__ W_hh, const float* __restrict__ WT,
    const float* __restrict__ W_rk, const float* __restrict__ b_rk,
    const float* __restrict__ W_wk, const float* __restrict__ b_wk,
    const float* __restrict__ W_wv, const float* __restrict__ b_wv,
    const float* __restrict__ W_er, const float* __restrict__ b_er,
    const float* __restrict__ G_emb, float* __restrict__ H_all,
    float* __restrict__ mem_row, float* __restrict__ memT,
    float* __restrict__ projbuf, float* __restrict__ gp_g,
    const float* __restrict__ W_out, const float* __restrict__ b_out,
    float* __restrict__ C_out, uint* __restrict__ arrv)
{
  __shared__ __align__(16) float smem[12384];   // 49.5 KB union
  const int tid = threadIdx.x;
  const int wg  = blockIdx.x;

  if (wg < NB_PROJ){
    // =================== PROJ / GATE role ===================
    float* hs = smem;              // [16][516]
    float* Ws = smem + 8256;       // [8][516]
    const int p1_b = tid >> 4, p1_col = tid & 15;
    const int pcol = wg*16 + p1_col;
    const int rrow = (pcol & 3)*512 + (pcol >> 2);
    const int msel = wg >> 5, col0 = (wg & 31)*8;
    const float* Wm  = (msel==0)? W_rk : (msel==1)? W_wk : (msel==2)? W_wv : W_er;
    const float* bmp = (msel==0)? b_rk : (msel==1)? b_wk : (msel==2)? b_wv : b_er;
    for (int i = tid; i < 8*HID; i += 256){
      int k = i >> 3, j = i & 7;
      Ws[j*516 + k] = Wm[(size_t)k*256 + col0 + j];
    }
    #pragma clang loop unroll(disable)
    for (int t = 0; t < T_STEPS-1; ++t){
      if (tid < 16) poll1(arrv + F_H(tid), (uint)(t+1));
      __syncthreads();
      const float4* hsrc = (const float4*)(H_all + (size_t)t*BQ*HID);
      for (int i = tid; i < 2048; i += 256){
        int b = i >> 7, q = i & 127;
        *(float4*)(hs + b*516 + q*4) = hsrc[i];   // fresh addresses each t: normal loads OK
      }
      __syncthreads();
      {  // projections
        int b = tid >> 4, o2 = (tid & 15) >> 1, half = tid & 1;
        const float4* wp = (const float4*)(Ws + o2*516 + half*256);
        const float4* xp = (const float4*)(hs + b*516 + half*256);
        float a0 = 0.f, a1 = 0.f;
        #pragma unroll 4
        for (int k = 0; k < 64; k += 2){
          float4 w = wp[k], x = xp[k];
          a0=fmaf(w.x,x.x,a0); a0=fmaf(w.y,x.y,a0); a0=fmaf(w.z,x.z,a0); a0=fmaf(w.w,x.w,a0);
          w = wp[k+1]; x = xp[k+1];
          a1=fmaf(w.x,x.x,a1); a1=fmaf(w.y,x.y,a1); a1=fmaf(w.z,x.z,a1); a1=fmaf(w.w,x.w,a1);
        }
        float acc = a0 + a1;
        float other = __shfl_xor(acc, 1);
        if (half == 0){
          float v = acc + other + bmp[col0 + o2];
          if (msel == 3) v = sigm(v);
          astoref(projbuf + (size_t)b*1024 + msel*256 + col0 + o2, v);
        }
      }
      arrive1(arrv + F_K(wg), (uint)(t+1));
      {  // gp(t+1) = G_emb[t+1] + W_hh·h_t
        float a0 = G_emb[(size_t)((t+1)*BQ + p1_b)*2048 + pcol];
        float a1 = 0.f, a2 = 0.f, a3 = 0.f;
        const float4* wh = (const float4*)(W_hh + (size_t)rrow*HID);
        const float4* xv = (const float4*)(hs + p1_b*516);
        #pragma unroll 2
        for (int k = 0; k < 128; k += 4){
          float4 w, x;
          w=wh[k+0]; x=xv[k+0]; a0=fmaf(w.x,x.x,a0); a0=fmaf(w.y,x.y,a0); a0=fmaf(w.z,x.z,a0); a0=fmaf(w.w,x.w,a0);
          w=wh[k+1]; x=xv[k+1]; a1=fmaf(w.x,x.x,a1); a1=fmaf(w.y,x.y,a1); a1=fmaf(w.z,x.z,a1); a1=fmaf(w.w,x.w,a1);
          w=wh[k+2]; x=xv[k+2]; a2=fmaf(w.x,x.x,a2); a2=fmaf(w.y,x.y,a2); a2=fmaf(w.z,x.z,a2); a2=fmaf(w.w,x.w,a2);
          w=wh[k+3]; x=xv[k+3]; a3=fmaf(w.x,x.x,a3); a3=fmaf(w.y,x.y,a3); a3=fmaf(w.z,x.z,a3); a3=fmaf(w.w,x.w,a3);
        }
        astoref(gp_g + (size_t)p1_b*2048 + pcol, (a0+a1)+(a2+a3));
      }
      arrive1(arrv + F_G(wg), (uint)(t+1));
    }
  } else if (wg < NB_REC){
    // =================== BATCH role ===================
    const int b = wg - NB_PROJ;
    float* keyT  = smem;                    // [64][8]
    float* wv_s  = smem + 512;              // 256 (+ er_s 256 contiguous)
    float* er_s  = smem + 768;
    float* rv_s  = smem + 1024;             // 64
    float* rvp   = smem + 1088;             // 1024
    float* wgt   = smem + 2112;             // 64
    int*   slotl = (int*)(smem + 2176);     // 64
    int*   ge_s  = (int*)(smem + 2240);     // 32
    float* knrm  = smem + 2272;             // 8
    u64*   cnd   = (u64*)(smem + 2280);     // 8*4*8 u64 = 512 floats -> ends 2792
    float* mrow = mem_row + (size_t)b*NSLOT*MD;
    float* mT   = memT    + (size_t)b*MD*NSLOT;

    // prologue: init memory + h_0
    {
      float4 iv = make_float4(1e-6f,1e-6f,1e-6f,1e-6f);
      for (int i = tid; i < NSLOT*MD/4; i += 256){
        *(float4*)(mrow + (size_t)i*4) = iv;
        *(float4*)(mT   + (size_t)i*4) = iv;
      }
    }
    float c0 = 0.f, c1 = 0.f;
    {
      float4 gA = *(const float4*)(G_emb + (size_t)b*2048 + tid*8);
      float4 gB = *(const float4*)(G_emb + (size_t)b*2048 + tid*8 + 4);
      c0 = sigm(gA.x)*tanhf(gA.z);
      float h0v = sigm(gA.w)*tanhf(c0);
      c1 = sigm(gB.x)*tanhf(gB.z);
      float h1v = sigm(gB.w)*tanhf(c1);
      astoref(H_all + (size_t)b*HID + tid*2,     h0v);
      astoref(H_all + (size_t)b*HID + tid*2 + 1, h1v);
    }
    asm volatile("s_waitcnt vmcnt(0)" ::: "memory");
    __syncthreads();
    if (tid == 0){ astoreu32(arrv + F_H(b), 1u); astoreu32(arrv + F_T(b), 1u); }

    const int lane = tid & 63, wv_id = tid >> 6;
    #pragma clang loop unroll(disable)
    for (int t = 0; t < T_STEPS-1; ++t){
      // ---- wait keys; stage projbuf[b] ----
      if (tid < 128) poll1(arrv + F_K(tid), (uint)(t+1));
      __syncthreads();
      {
        float4 v; AL4(v, (const float4*)(projbuf + (size_t)b*1024) + tid); AWAIT();
        if (tid < 128){
          int q = tid*4;
          keyT[((q+0)&63)*8 + ((q+0)>>6)] = v.x;
          keyT[((q+1)&63)*8 + ((q+1)>>6)] = v.y;
          keyT[((q+2)&63)*8 + ((q+2)>>6)] = v.z;
          keyT[((q+3)&63)*8 + ((q+3)>>6)] = v.w;
        } else {
          *(float4*)(wv_s + (tid-128)*4) = v;    // wv then er (contiguous)
        }
      }
      __syncthreads();
      if (tid < 8){
        float kn = 0.f;
        #pragma unroll 8
        for (int d = 0; d < 64; ++d){ float kv = keyT[d*8 + tid]; kn = fmaf(kv,kv,kn); }
        knrm[tid] = 1.f / (sqrtf(kn) + EPSN);
      }
      // ---- scores: 4 slots/thread x 8 keys ----
      float ss0=0,ss1=0,ss2=0,ss3=0;
      float sc[8][4] = {};
      {
        const float* mp = mT + tid;
        #pragma unroll 2
        for (int d = 0; d < 64; ++d){
          float4 ka = *(const float4*)(keyT + d*8);
          float4 kb = *(const float4*)(keyT + d*8 + 4);
          float m0 = mp[d*1024], m1 = mp[d*1024+256], m2 = mp[d*1024+512], m3 = mp[d*1024+768];
          ss0=fmaf(m0,m0,ss0); ss1=fmaf(m1,m1,ss1); ss2=fmaf(m2,m2,ss2); ss3=fmaf(m3,m3,ss3);
          sc[0][0]=fmaf(m0,ka.x,sc[0][0]); sc[0][1]=fmaf(m1,ka.x,sc[0][1]); sc[0][2]=fmaf(m2,ka.x,sc[0][2]); sc[0][3]=fmaf(m3,ka.x,sc[0][3]);
          sc[1][0]=fmaf(m0,ka.y,sc[1][0]); sc[1][1]=fmaf(m1,ka.y,sc[1][1]); sc[1][2]=fmaf(m2,ka.y,sc[1][2]); sc[1][3]=fmaf(m3,ka.y,sc[1][3]);
          sc[2][0]=fmaf(m0,ka.z,sc[2][0]); sc[2][1]=fmaf(m1,ka.z,sc[2][1]); sc[2][2]=fmaf(m2,ka.z,sc[2][2]); sc[2][3]=fmaf(m3,ka.z,sc[2][3]);
          sc[3][0]=fmaf(m0,ka.w,sc[3][0]); sc[3][1]=fmaf(m1,ka.w,sc[3][1]); sc[3][2]=fmaf(m2,ka.w,sc[3][2]); sc[3][3]=fmaf(m3,ka.w,sc[3][3]);
          sc[4][0]=fmaf(m0,kb.x,sc[4][0]); sc[4][1]=fmaf(m1,kb.x,sc[4][1]); sc[4][2]=fmaf(m2,kb.x,sc[4][2]); sc[4][3]=fmaf(m3,kb.x,sc[4][3]);
          sc[5][0]=fmaf(m0,kb.y,sc[5][0]); sc[5][1]=fmaf(m1,kb.y,sc[5][1]); sc[5][2]=fmaf(m2,kb.y,sc[5][2]); sc[5][3]=fmaf(m3,kb.y,sc[5][3]);
          sc[6][0]=fmaf(m0,kb.z,sc[6][0]); sc[6][1]=fmaf(m1,kb.z,sc[6][1]); sc[6][2]=fmaf(m2,kb.z,sc[6][2]); sc[6][3]=fmaf(m3,kb.z,sc[6][3]);
          sc[7][0]=fmaf(m0,kb.w,sc[7][0]); sc[7][1]=fmaf(m1,kb.w,sc[7][1]); sc[7][2]=fmaf(m2,kb.w,sc[7][2]); sc[7][3]=fmaf(m3,kb.w,sc[7][3]);
        }
      }
      float rn0 = BETA/(sqrtf(ss0)+EPSN), rn1 = BETA/(sqrtf(ss1)+EPSN);
      float rn2 = BETA/(sqrtf(ss2)+EPSN), rn3 = BETA/(sqrtf(ss3)+EPSN);
      // ---- per-wave top8 per key (registers only) ----
      #pragma unroll
      for (int key = 0; key < 8; ++key){
        u64 p0 = packsc(sc[key][0]*rn0, tid);
        u64 p1 = packsc(sc[key][1]*rn1, tid+256);
        u64 p2 = packsc(sc[key][2]*rn2, tid+512);
        u64 p3 = packsc(sc[key][3]*rn3, tid+768);
        #pragma unroll
        for (int r = 0; r < 8; ++r){
          u64 m01 = p0 > p1 ? p0 : p1;
          u64 m23 = p2 > p3 ? p2 : p3;
          u64 m = m01 > m23 ? m01 : m23;
          #pragma unroll
          for (int o = 32; o; o >>= 1){ u64 q = __shfl_xor(m, o); if (q > m) m = q; }
          if (p0 == m) p0 = 0; else if (p1 == m) p1 = 0;
          else if (p2 == m) p2 = 0; else if (p3 == m) p3 = 0;
          if (lane == 0) cnd[(key*4 + wv_id)*8 + r] = m;
        }
      }
      __syncthreads();
      // ---- merge 4 sorted lists + softmax (8 threads) ----
      if (tid < 8){
        const u64* cl = cnd + tid*32;
        int i0=0,i1=0,i2=0,i3=0;
        float vals[8]; int sl[8];
        #pragma unroll
        for (int r = 0; r < 8; ++r){
          u64 a = cl[i0], bb2 = cl[8+i1], c = cl[16+i2], d = cl[24+i3];
          u64 m1_ = a > bb2 ? a : bb2;
          u64 m2_ = c > d ? c : d;
          u64 m = m1_ > m2_ ? m1_ : m2_;
          if (m == a) ++i0; else if (m == bb2) ++i1; else if (m == c) ++i2; else ++i3;
          vals[r] = unpackval(m) * knrm[tid];
          sl[r]   = unpackslot(m);
        }
        float vm = vals[0], et[8], sum = 0.f;
        #pragma unroll
        for (int r = 0; r < 8; ++r){ et[r] = expf(vals[r]-vm); sum += et[r]; }
        float rs = 1.f/sum;
        #pragma unroll
        for (int r = 0; r < 8; ++r){ wgt[tid*8+r] = et[r]*rs; slotl[tid*8+r] = sl[r]; }
      }
      __syncthreads();
      // ---- rv partials (pre-write) + write-dedup map ----
      #pragma unroll
      for (int jj = 0; jj < 4; ++jj){
        int it = tid + 256*jj;
        int hh = it >> 8, rr = (it >> 6) & 3, d = it & 63;
        float w0 = wgt[hh*8+rr],   w1 = wgt[hh*8+rr+4];
        int   s0 = slotl[hh*8+rr], s1 = slotl[hh*8+rr+4];
        rvp[it] = w0*mrow[(size_t)s0*64+d] + w1*mrow[(size_t)s1*64+d];
      }
      if (tid < 32){
        int me = slotl[32+tid], g = tid;
        for (int e = 0; e < 32; ++e){ if (e < tid && slotl[32+e] == me){ g = e; break; } }
        ge_s[tid] = g;
      }
      __syncthreads();
      // rv finalize
      if (tid < 64){
        float s = 0.f;
        #pragma unroll
        for (int i = 0; i < 16; ++i) s += rvp[i*64 + tid];
        rv_s[tid] = 0.25f*s;
      }
      // erase+add (closed form per unique slot)
      #pragma unroll
      for (int jj = 0; jj < 8; ++jj){
        int it = tid + 256*jj;          // (g,d)
        int g = it >> 6, d = it & 63;
        if (ge_s[g] == g){
          float keep = 1.f, add = 0.f;
          for (int e = 0; e < 32; ++e){
            if (ge_s[e] == g){
              float w = wgt[32+e]; int h = e >> 3;
              keep *= (1.f - w*er_s[h*64+d]);
              add  += w*wv_s[h*64+d];
            }
          }
          int slot = slotl[32+g];
          float nv = mrow[(size_t)slot*64+d]*keep + add;
          mrow[(size_t)slot*64+d] = nv;
          mT[(size_t)d*1024+slot] = nv;
        }
      }
      __syncthreads();
      // ---- gates = gp + WT·rv ; LSTM ; publish h_{t+1} ----
      if (tid < 128) poll1(arrv + F_G(tid), (uint)(t+1));
      __syncthreads();
      float ga0,ga1,ga2,ga3,ga4,ga5,ga6,ga7;
      {
        float4 g0, g1;
        AL4(g0, (const float4*)(gp_g + (size_t)b*2048 + tid*8));
        AL4(g1, (const float4*)(gp_g + (size_t)b*2048 + tid*8 + 4));
        AWAIT();
        ga0=g0.x; ga1=g0.y; ga2=g0.z; ga3=g0.w; ga4=g1.x; ga5=g1.y; ga6=g1.z; ga7=g1.w;
      }
      {
        const float4* wt = (const float4*)(WT + tid*8);
        #pragma unroll 4
        for (int d = 0; d < 64; ++d){
          float r = rv_s[d];
          float4 w0 = wt[d*512], w1 = wt[d*512 + 1];
          ga0=fmaf(r,w0.x,ga0); ga1=fmaf(r,w0.y,ga1); ga2=fmaf(r,w0.z,ga2); ga3=fmaf(r,w0.w,ga3);
          ga4=fmaf(r,w1.x,ga4); ga5=fmaf(r,w1.y,ga5); ga6=fmaf(r,w1.z,ga6); ga7=fmaf(r,w1.w,ga7);
        }
      }
      c0 = sigm(ga1)*c0 + sigm(ga0)*tanhf(ga2);
      float h0v = sigm(ga3)*tanhf(c0);
      c1 = sigm(ga5)*c1 + sigm(ga4)*tanhf(ga6);
      float h1v = sigm(ga7)*tanhf(c1);
      astoref(H_all + (size_t)((t+1)*BQ + b)*HID + tid*2,     h0v);
      astoref(H_all + (size_t)((t+1)*BQ + b)*HID + tid*2 + 1, h1v);
      asm volatile("s_waitcnt vmcnt(0)" ::: "memory");
      __syncthreads();
      if (tid == 0){ astoreu32(arrv + F_H(b), (uint)(t+2)); astoreu32(arrv + F_T(b), (uint)(t+2)); }
    }
  } else {
    // =================== GEMM role: logits tile ===================
    int gb = wg - NB_REC;
    int mt = gb / GEMM_NT, nt = gb - mt*GEMM_NT;
    int m0 = mt*128, n0 = nt*64;
    uint need = (uint)(mt*8 + 8);          // h up to t=mt*8+7
    if (tid < 16) poll64(arrv + F_T(tid), need);
    __syncthreads();
    float* As = smem;            // [16][132]
    float* Bs = smem + 2112;     // [16][64]
    int tx = tid & 15, ty = tid >> 4;
    float acc[8][4] = {};
    for (int k0 = 0; k0 < 512; k0 += 16){
      int mm = tid >> 1, kq = (tid & 1)*8;
      float4 a0 = *(const float4*)(H_all + (size_t)(m0+mm)*512 + k0 + kq);
      float4 a1 = *(const float4*)(H_all + (size_t)(m0+mm)*512 + k0 + kq + 4);
      As[(kq+0)*132+mm]=a0.x; As[(kq+1)*132+mm]=a0.y; As[(kq+2)*132+mm]=a0.z; As[(kq+3)*132+mm]=a0.w;
      As[(kq+4)*132+mm]=a1.x; As[(kq+5)*132+mm]=a1.y; As[(kq+6)*132+mm]=a1.z; As[(kq+7)*132+mm]=a1.w;
      int kk2 = tid >> 4, nq = (tid & 15)*4;
      *(float4*)(Bs + kk2*64 + nq) = *(const float4*)(W_out + (size_t)(k0+kk2)*VOCAB + n0 + nq);
      __syncthreads();
      #pragma unroll
      for (int kk = 0; kk < 16; ++kk){
        float4 x0 = *(const float4*)(As + kk*132 + ty*8);
        float4 x1 = *(const float4*)(As + kk*132 + ty*8 + 4);
        float4 bv = *(const float4*)(Bs + kk*64 + tx*4);
        float aa[8] = {x0.x,x0.y,x0.z,x0.w,x1.x,x1.y,x1.z,x1.w};
        float bb[4] = {bv.x,bv.y,bv.z,bv.w};
        #pragma unroll
        for (int i = 0; i < 8; ++i)
          #pragma unroll
          for (int j = 0; j < 4; ++j)
            acc[i][j] = fmaf(aa[i], bb[j], acc[i][j]);
      }
      __syncthreads();
    }
    #pragma unroll
    for (int i = 0; i < 8; ++i){
      int m = m0 + ty*8 + i;
      int bq = m & 15, tt = m >> 4;
      float* crow = C_out + ((size_t)bq*T_STEPS + tt)*VOCAB + n0 + tx*4;
      #pragma unroll
      for (int j = 0; j < 4; ++j) crow[j] = acc[i][j] + b_out[n0 + tx*4 + j];
    }
  }
}

extern "C" void kernel_launch(void* const* d_in, const int* in_sizes, int n_in,
                              void* d_out, int out_size, void* d_ws, size_t ws_size,
                              hipStream_t stream){
  const int*   seq   = (const int*)d_in[0];
  const float* E     = (const float*)d_in[1];
  const float* W_ih  = (const float*)d_in[2];
  const float* W_hh  = (const float*)d_in[3];
  const float* b_ih  = (const float*)d_in[4];
  const float* b_hh  = (const float*)d_in[5];
  const float* W_out = (const float*)d_in[6];
  const float* b_out = (const float*)d_in[7];
  const float* W_rk  = (const float*)d_in[8];
  const float* b_rk  = (const float*)d_in[9];
  const float* W_wk  = (const float*)d_in[10];
  const float* b_wk  = (const float*)d_in[11];
  const float* W_wv  = (const float*)d_in[12];
  const float* b_wv  = (const float*)d_in[13];
  const float* W_er  = (const float*)d_in[14];
  const float* b_er  = (const float*)d_in[15];
  float* out = (float*)d_out;
  (void)in_sizes; (void)n_in; (void)out_size; (void)ws_size;

  char* ws = (char*)d_ws;
  size_t off = 0;
  auto alloc = [&](size_t bytes) -> void* {
    off = (off + 255) & ~(size_t)255;
    void* p = ws + off;
    off += bytes;
    return p;
  };
  float* EMB     = (float*)alloc((size_t)2048*256*4);
  float* G_emb   = (float*)alloc((size_t)2048*2048*4);
  float* H_all   = (float*)alloc((size_t)2048*512*4);
  float* mem_row = (float*)alloc((size_t)16*1024*64*4);
  float* memT    = (float*)alloc((size_t)16*64*1024*4);
  float* projbuf = (float*)alloc((size_t)16*1024*4);
  float* gp_g    = (float*)alloc((size_t)16*2048*4);
  float* WT      = (float*)alloc((size_t)64*2048*4);
  uint*  arrv    = (uint*)alloc((size_t)NFLAGS*32*4);

  hipMemsetAsync(arrv, 0, (size_t)NFLAGS*32*4, stream);
  prep_emb<<<2048, 256, 0, stream>>>(E, seq, EMB);
  gemm_emb<<<1024, 256, 0, stream>>>(EMB, W_ih, b_ih, b_hh, G_emb);
  make_wrvT<<<512, 256, 0, stream>>>(W_ih, WT);
  mega_kernel<<<NB_REC + NB_GEMM, 256, 0, stream>>>(
      W_hh, WT, W_rk, b_rk, W_wk, b_wk, W_wv, b_wv, W_er, b_er,
      G_emb, H_all, mem_row, memT, projbuf, gp_g,
      W_out, b_out, out, arrv);
}